// Round 3
// baseline (845.724 us; speedup 1.0000x reference)
//
#include <hip/hip_runtime.h>
#include <hip/hip_bf16.h>

// CRF-as-RNN mean-field on MI355X. B=2, L=21, C=3, H=W=96, N=9216, NITERS=5.
//
// w[n][m] = exp2(gs[m] + f_n . fs[m])  (log2e pre-scaled; the row factor
// cancels under row normalization). Per iter:
//   P[n][l] = sum_m w[n][m]*MQ[l][m]  via bf16 MFMA 16x16x32, with the
//   A-fragment (w) GENERATED IN REGISTERS (no LDS, no barriers) and the
//   B-fragment loaded straight from global MQ.
// MQ is padded to 32 channels: ch 21 = 1.0 -> P[.,21] = rowsum (free),
// ch 22..31 = 0. msg = P/P[21]; Q = softmax_l(-(E0+msg)); MQ = Mu@Q (bf16).

#define BB 2
#define LL 21
#define LCH 32              // padded channel count of MQ
#define LLP 22              // channels stored in Ppart (21 + rowsum)
#define NNPX 9216
#define NITERS 5
#define LOG2E 1.4426950408889634f

typedef __attribute__((ext_vector_type(8))) short short8;
typedef __attribute__((ext_vector_type(4))) float f32x4;

static __device__ inline unsigned int pk_bf16(float a, float b) {
    __hip_bfloat162 h = __float22bfloat162_rn(make_float2(a, b));
    unsigned int u;
    __builtin_memcpy(&u, &h, 4);
    return u;
}

// ---------------- prep: features + Q0 + MQ0(bf16, padded) ----------------
__global__ __launch_bounds__(256) void k_prep(
        const float* __restrict__ E0, const float* __restrict__ Refs,
        const float* __restrict__ Mu,
        float4* __restrict__ FN, float4* __restrict__ FS,
        __hip_bfloat16* __restrict__ MQ) {
    __shared__ float muS[LL * LL];
    for (int i = threadIdx.x; i < LL * LL; i += 256) muS[i] = Mu[i];
    __syncthreads();

    int idx = blockIdx.x * 256 + threadIdx.x;      // b*N + n
    int b = idx / NNPX, n = idx % NNPX;

    const float* rb = Refs + (size_t)b * 3 * NNPX + n;
    float r0 = rb[0], r1 = rb[NNPX], r2 = rb[2 * NNPX];
    FN[idx] = make_float4(r0, r1, r2, 0.f);
    float g = -0.5f * (r0 * r0 + r1 * r1 + r2 * r2);
    FS[idx] = make_float4(g * LOG2E, r0 * LOG2E, r1 * LOG2E, r2 * LOG2E);

    const float* eb = E0 + (size_t)b * LL * NNPX + n;
    float x[LL];
    float mx = -1e30f;
    for (int l = 0; l < LL; ++l) { x[l] = -eb[(size_t)l * NNPX]; mx = fmaxf(mx, x[l]); }
    float s = 0.f;
    for (int l = 0; l < LL; ++l) { x[l] = __builtin_amdgcn_exp2f((x[l] - mx) * LOG2E); s += x[l]; }
    float rs = __builtin_amdgcn_rcpf(s);
    for (int l = 0; l < LL; ++l) x[l] *= rs;

    __hip_bfloat16* mq = MQ + (size_t)b * LCH * NNPX + n;
    for (int k = 0; k < LL; ++k) {
        float a = 0.f;
        for (int l = 0; l < LL; ++l) a += muS[k * LL + l] * x[l];
        mq[(size_t)k * NNPX] = __float2bfloat16(a);
    }
    mq[(size_t)21 * NNPX] = __float2bfloat16(1.0f);    // ones column -> rowsum
    for (int k = 22; k < LCH; ++k) mq[(size_t)k * NNPX] = __float2bfloat16(0.0f);
}

// ---------------- accumulate via MFMA, barrier-free ----------------
// grid (288, S): blockIdx.x = b*144 + n-tile(64 rows); wave handles 16 rows.
// m handled in chunks of 32 (one MFMA pair); split s takes chunks s, s+S, ...
__global__ __launch_bounds__(256) void k_accum(
        const float4* __restrict__ FS, const float4* __restrict__ FN,
        const unsigned short* __restrict__ MQbf, float* __restrict__ Ppart, int S) {
    int t = threadIdx.x;
    int rb = blockIdx.x;
    int s  = blockIdx.y;
    int b  = rb / 144;
    int n0 = (rb % 144) * 64;
    int wv = t >> 6, lane = t & 63;
    int col = lane & 15, q = lane >> 4;

    float4 fn = FN[b * NNPX + n0 + wv * 16 + col];
    const float4* fsb = FS + (size_t)b * NNPX;
    const unsigned short* mq0 = MQbf + (size_t)b * LCH * NNPX + (size_t)col * NNPX;
    const unsigned short* mq1 = mq0 + (size_t)16 * NNPX;

    f32x4 acc0 = {0.f, 0.f, 0.f, 0.f};   // l = 0..15
    f32x4 acc1 = {0.f, 0.f, 0.f, 0.f};   // l = 16..31 (21 = rowsum)

    for (int c = s; c < 288; c += S) {
        int kb = c * 32 + q * 8;          // this lane's 8 m-indices
        float w0, w1, w2, w3, w4, w5, w6, w7;
        {
            float4 F0 = fsb[kb + 0], F1 = fsb[kb + 1], F2 = fsb[kb + 2], F3 = fsb[kb + 3];
            float4 F4 = fsb[kb + 4], F5 = fsb[kb + 5], F6 = fsb[kb + 6], F7 = fsb[kb + 7];
            w0 = __builtin_amdgcn_exp2f(F0.x + fn.x * F0.y + fn.y * F0.z + fn.z * F0.w);
            w1 = __builtin_amdgcn_exp2f(F1.x + fn.x * F1.y + fn.y * F1.z + fn.z * F1.w);
            w2 = __builtin_amdgcn_exp2f(F2.x + fn.x * F2.y + fn.y * F2.z + fn.z * F2.w);
            w3 = __builtin_amdgcn_exp2f(F3.x + fn.x * F3.y + fn.y * F3.z + fn.z * F3.w);
            w4 = __builtin_amdgcn_exp2f(F4.x + fn.x * F4.y + fn.y * F4.z + fn.z * F4.w);
            w5 = __builtin_amdgcn_exp2f(F5.x + fn.x * F5.y + fn.y * F5.z + fn.z * F5.w);
            w6 = __builtin_amdgcn_exp2f(F6.x + fn.x * F6.y + fn.y * F6.z + fn.z * F6.w);
            w7 = __builtin_amdgcn_exp2f(F7.x + fn.x * F7.y + fn.y * F7.z + fn.z * F7.w);
        }
        union { unsigned int u[4]; short8 v; } af;
        af.u[0] = pk_bf16(w0, w1);
        af.u[1] = pk_bf16(w2, w3);
        af.u[2] = pk_bf16(w4, w5);
        af.u[3] = pk_bf16(w6, w7);
        short8 bf0 = *(const short8*)&mq0[kb];
        short8 bf1 = *(const short8*)&mq1[kb];
        acc0 = __builtin_amdgcn_mfma_f32_16x16x32_bf16(af.v, bf0, acc0, 0, 0, 0);
        acc1 = __builtin_amdgcn_mfma_f32_16x16x32_bf16(af.v, bf1, acc1, 0, 0, 0);
    }

    // epilogue: C layout col=lane&15, row=(lane>>4)*4+reg  (validated R2)
    float* pp = Ppart + (size_t)(s * BB + b) * LLP * NNPX;
    int nb = n0 + wv * 16 + q * 4;
    for (int r = 0; r < 4; ++r) {
        pp[(size_t)col * NNPX + nb + r] = acc0[r];
        if (col < LLP - 16) pp[(size_t)(16 + col) * NNPX + nb + r] = acc1[r];
    }
}

// ---------------- reduce partials + softmax + Potts mix ----------------
template <bool LAST>
__global__ __launch_bounds__(256) void k_softmax(
        const float* __restrict__ E0, const float* __restrict__ Ppart,
        const float* __restrict__ Mu,
        __hip_bfloat16* __restrict__ MQ, float* __restrict__ Out, int S) {
    __shared__ float muS[LL * LL];
    for (int i = threadIdx.x; i < LL * LL; i += 256) muS[i] = Mu[i];
    __syncthreads();

    int idx = blockIdx.x * 256 + threadIdx.x;
    int b = idx / NNPX, n = idx % NNPX;

    float P[LLP];
    for (int l = 0; l < LLP; ++l) P[l] = 0.f;
    for (int s = 0; s < S; ++s) {
        const float* pp = Ppart + (size_t)(s * BB + b) * LLP * NNPX + n;
        for (int l = 0; l < LLP; ++l) P[l] += pp[(size_t)l * NNPX];
    }
    float rinv = __builtin_amdgcn_rcpf(P[21]);   // rowsum channel

    const float* eb = E0 + (size_t)b * LL * NNPX + n;
    float mx = -1e30f;
    for (int l = 0; l < LL; ++l) {
        P[l] = -(eb[(size_t)l * NNPX] + P[l] * rinv);
        mx = fmaxf(mx, P[l]);
    }
    float ssum = 0.f;
    for (int l = 0; l < LL; ++l) { P[l] = __builtin_amdgcn_exp2f((P[l] - mx) * LOG2E); ssum += P[l]; }
    float rs = __builtin_amdgcn_rcpf(ssum);
    for (int l = 0; l < LL; ++l) P[l] *= rs;

    if (LAST) {
        float* ob = Out + (size_t)b * LL * NNPX + n;
        for (int l = 0; l < LL; ++l) ob[(size_t)l * NNPX] = P[l];
    } else {
        __hip_bfloat16* mq = MQ + (size_t)b * LCH * NNPX + n;
        for (int k = 0; k < LL; ++k) {
            float a = 0.f;
            for (int l = 0; l < LL; ++l) a += muS[k * LL + l] * P[l];
            mq[(size_t)k * NNPX] = __float2bfloat16(a);
        }
        // channels 21..31 keep their k_prep values (1.0, zeros)
    }
}

extern "C" void kernel_launch(void* const* d_in, const int* in_sizes, int n_in,
                              void* d_out, int out_size, void* d_ws, size_t ws_size,
                              hipStream_t stream) {
    const float* E0   = (const float*)d_in[0];
    const float* Refs = (const float*)d_in[1];
    const float* Mu   = (const float*)d_in[2];
    float* out = (float*)d_out;

    char* w = (char*)d_ws;
    size_t off = 0;
    auto alloc = [&](size_t bytes) {
        void* p = w + off;
        off += (bytes + 255) & ~(size_t)255;
        return p;
    };
    float4* FN = (float4*)alloc((size_t)BB * NNPX * sizeof(float4));
    float4* FS = (float4*)alloc((size_t)BB * NNPX * sizeof(float4));
    __hip_bfloat16* MQbf = (__hip_bfloat16*)alloc((size_t)BB * LCH * NNPX * sizeof(__hip_bfloat16));

    // m-split S whose partial buffer fits in remaining ws (cap 8)
    size_t per = (size_t)BB * LLP * NNPX * sizeof(float);
    size_t avail = ws_size > off ? ws_size - off : 0;
    int Smax = (int)(avail / (per + 256));
    static const int divs[] = {8, 6, 4, 3, 2, 1};
    int S = 1;
    for (int i = 0; i < 6; ++i) if (divs[i] <= Smax) { S = divs[i]; break; }
    float* Ppart = (float*)alloc((size_t)S * per);

    k_prep<<<BB * NNPX / 256, 256, 0, stream>>>(E0, Refs, Mu, FN, FS, MQbf);
    for (int it = 0; it < NITERS; ++it) {
        k_accum<<<dim3(288, S), 256, 0, stream>>>(FS, FN, (const unsigned short*)MQbf, Ppart, S);
        if (it == NITERS - 1)
            k_softmax<true><<<BB * NNPX / 256, 256, 0, stream>>>(E0, Ppart, Mu, MQbf, out, S);
        else
            k_softmax<false><<<BB * NNPX / 256, 256, 0, stream>>>(E0, Ppart, Mu, MQbf, out, S);
    }
}

// Round 4
// 597.366 us; speedup vs baseline: 1.4158x; 1.4158x over previous
//
#include <hip/hip_runtime.h>
#include <hip/hip_bf16.h>

// CRF-as-RNN mean-field on MI355X. B=2, L=21, C=3, H=W=96, N=9216, NITERS=5.
//
// w[n][m] = exp2(gs[m] + f_n . fs[m])  (log2e pre-scaled; the row factor
// cancels under row normalization). Per iter:
//   P[n][l] = sum_m w[n][m]*MQ[l][m]  via bf16 MFMA 16x16x32.
// A-fragment (w) generated IN REGISTERS (validated R3); B-tile (MQ) staged
// through LDS with coalesced loads (validated R2 — global fragment loads are
// uncoalesced 64-line disasters, R3's regression).
// MQ padded to 32 channels: ch21 = 1.0 -> P[.,21] = rowsum (free), ch22..31 = 0.
// msg = P/P[21]; Q = softmax_l(-(E0+msg)); MQ = Mu@Q (bf16).

#define BB 2
#define LL 21
#define LCH 32              // padded channel count of MQ
#define LLP 22              // channels stored in Ppart (21 + rowsum)
#define NNPX 9216
#define NITERS 5
#define LOG2E 1.4426950408889634f
#define BSTR 264            // LDS B-tile row stride in shorts (256 + 8 pad)

typedef __attribute__((ext_vector_type(8))) short short8;
typedef __attribute__((ext_vector_type(4))) float f32x4;

static __device__ inline unsigned int pk_bf16(float a, float b) {
    __hip_bfloat162 h = __float22bfloat162_rn(make_float2(a, b));
    unsigned int u;
    __builtin_memcpy(&u, &h, 4);
    return u;
}

// ---------------- prep: features + Q0 + MQ0(bf16, padded) ----------------
__global__ __launch_bounds__(256) void k_prep(
        const float* __restrict__ E0, const float* __restrict__ Refs,
        const float* __restrict__ Mu,
        float4* __restrict__ FN, float4* __restrict__ FS,
        __hip_bfloat16* __restrict__ MQ) {
    __shared__ float muS[LL * LL];
    for (int i = threadIdx.x; i < LL * LL; i += 256) muS[i] = Mu[i];
    __syncthreads();

    int idx = blockIdx.x * 256 + threadIdx.x;      // b*N + n
    int b = idx / NNPX, n = idx % NNPX;

    const float* rb = Refs + (size_t)b * 3 * NNPX + n;
    float r0 = rb[0], r1 = rb[NNPX], r2 = rb[2 * NNPX];
    FN[idx] = make_float4(r0, r1, r2, 0.f);
    float g = -0.5f * (r0 * r0 + r1 * r1 + r2 * r2);
    FS[idx] = make_float4(g * LOG2E, r0 * LOG2E, r1 * LOG2E, r2 * LOG2E);

    const float* eb = E0 + (size_t)b * LL * NNPX + n;
    float x[LL];
    float mx = -1e30f;
    for (int l = 0; l < LL; ++l) { x[l] = -eb[(size_t)l * NNPX]; mx = fmaxf(mx, x[l]); }
    float s = 0.f;
    for (int l = 0; l < LL; ++l) { x[l] = __builtin_amdgcn_exp2f((x[l] - mx) * LOG2E); s += x[l]; }
    float rs = __builtin_amdgcn_rcpf(s);
    for (int l = 0; l < LL; ++l) x[l] *= rs;

    __hip_bfloat16* mq = MQ + (size_t)b * LCH * NNPX + n;
    for (int k = 0; k < LL; ++k) {
        float a = 0.f;
        for (int l = 0; l < LL; ++l) a += muS[k * LL + l] * x[l];
        mq[(size_t)k * NNPX] = __float2bfloat16(a);
    }
    mq[(size_t)21 * NNPX] = __float2bfloat16(1.0f);    // ones column -> rowsum
    for (int k = 22; k < LCH; ++k) mq[(size_t)k * NNPX] = __float2bfloat16(0.0f);
}

// ---------------- accumulate via MFMA: reg A-gen + LDS B ----------------
// grid (288, S): blockIdx.x = b*144 + n-tile(64 rows); wave handles 16 rows.
// m in chunks of 256 (36 chunks); split s takes chunks s, s+S, ...
// Per chunk: stage B[32ch][256m] bf16 into LDS (coalesced), then 8 k-steps.
__global__ __launch_bounds__(256) void k_accum(
        const float4* __restrict__ FS, const float4* __restrict__ FN,
        const unsigned short* __restrict__ MQbf, float* __restrict__ Ppart, int S) {
    __shared__ __align__(16) unsigned short Mlds[32 * BSTR];

    int t = threadIdx.x;
    int rb = blockIdx.x;
    int s  = blockIdx.y;
    int b  = rb / 144;
    int n0 = (rb % 144) * 64;
    int wv = t >> 6, lane = t & 63;
    int col = lane & 15, q = lane >> 4;

    float4 fn = FN[b * NNPX + n0 + wv * 16 + col];
    const float4* fsb = FS + (size_t)b * NNPX;
    const unsigned short* mqb = MQbf + (size_t)b * LCH * NNPX;

    // staging map: element e = t + 256*i -> row l = e>>5, 16B-seg sg = e&31
    int sl[4], ss[4];
    for (int i = 0; i < 4; ++i) { int e = t + 256 * i; sl[i] = e >> 5; ss[i] = e & 31; }

    f32x4 acc0 = {0.f, 0.f, 0.f, 0.f};   // l = 0..15
    f32x4 acc1 = {0.f, 0.f, 0.f, 0.f};   // l = 16..31 (21 = rowsum)

    for (int c = s; c < 36; c += S) {
        int m0 = c * 256;
        __syncthreads();   // previous chunk's B reads done
        for (int i = 0; i < 4; ++i) {
            uint4 v = *(const uint4*)&mqb[(size_t)sl[i] * NNPX + m0 + ss[i] * 8];
            *(uint4*)&Mlds[sl[i] * BSTR + ss[i] * 8] = v;
        }
        __syncthreads();   // B staged

        for (int ks = 0; ks < 8; ++ks) {
            int kb = m0 + ks * 32 + q * 8;          // this lane's 8 m-indices
            float4 F0 = fsb[kb + 0], F1 = fsb[kb + 1], F2 = fsb[kb + 2], F3 = fsb[kb + 3];
            float4 F4 = fsb[kb + 4], F5 = fsb[kb + 5], F6 = fsb[kb + 6], F7 = fsb[kb + 7];
            float w0 = __builtin_amdgcn_exp2f(F0.x + fn.x * F0.y + fn.y * F0.z + fn.z * F0.w);
            float w1 = __builtin_amdgcn_exp2f(F1.x + fn.x * F1.y + fn.y * F1.z + fn.z * F1.w);
            float w2 = __builtin_amdgcn_exp2f(F2.x + fn.x * F2.y + fn.y * F2.z + fn.z * F2.w);
            float w3 = __builtin_amdgcn_exp2f(F3.x + fn.x * F3.y + fn.y * F3.z + fn.z * F3.w);
            float w4 = __builtin_amdgcn_exp2f(F4.x + fn.x * F4.y + fn.y * F4.z + fn.z * F4.w);
            float w5 = __builtin_amdgcn_exp2f(F5.x + fn.x * F5.y + fn.y * F5.z + fn.z * F5.w);
            float w6 = __builtin_amdgcn_exp2f(F6.x + fn.x * F6.y + fn.y * F6.z + fn.z * F6.w);
            float w7 = __builtin_amdgcn_exp2f(F7.x + fn.x * F7.y + fn.y * F7.z + fn.z * F7.w);
            union { unsigned int u[4]; short8 v; } af;
            af.u[0] = pk_bf16(w0, w1);
            af.u[1] = pk_bf16(w2, w3);
            af.u[2] = pk_bf16(w4, w5);
            af.u[3] = pk_bf16(w6, w7);
            int ko = ks * 32 + q * 8;
            short8 bf0 = *(const short8*)&Mlds[col * BSTR + ko];
            short8 bf1 = *(const short8*)&Mlds[(16 + col) * BSTR + ko];
            acc0 = __builtin_amdgcn_mfma_f32_16x16x32_bf16(af.v, bf0, acc0, 0, 0, 0);
            acc1 = __builtin_amdgcn_mfma_f32_16x16x32_bf16(af.v, bf1, acc1, 0, 0, 0);
        }
    }

    // epilogue: C layout col=lane&15, row=(lane>>4)*4+reg  (validated R2/R3)
    float* pp = Ppart + (size_t)(s * BB + b) * LLP * NNPX;
    int nb = n0 + wv * 16 + q * 4;
    for (int r = 0; r < 4; ++r) {
        pp[(size_t)col * NNPX + nb + r] = acc0[r];
        if (col < LLP - 16) pp[(size_t)(16 + col) * NNPX + nb + r] = acc1[r];
    }
}

// ---------------- reduce partials + softmax + Potts mix ----------------
template <bool LAST>
__global__ __launch_bounds__(256) void k_softmax(
        const float* __restrict__ E0, const float* __restrict__ Ppart,
        const float* __restrict__ Mu,
        __hip_bfloat16* __restrict__ MQ, float* __restrict__ Out, int S) {
    __shared__ float muS[LL * LL];
    for (int i = threadIdx.x; i < LL * LL; i += 256) muS[i] = Mu[i];
    __syncthreads();

    int idx = blockIdx.x * 256 + threadIdx.x;
    int b = idx / NNPX, n = idx % NNPX;

    float P[LLP];
    for (int l = 0; l < LLP; ++l) P[l] = 0.f;
    for (int s = 0; s < S; ++s) {
        const float* pp = Ppart + (size_t)(s * BB + b) * LLP * NNPX + n;
        for (int l = 0; l < LLP; ++l) P[l] += pp[(size_t)l * NNPX];
    }
    float rinv = __builtin_amdgcn_rcpf(P[21]);   // rowsum channel

    const float* eb = E0 + (size_t)b * LL * NNPX + n;
    float mx = -1e30f;
    for (int l = 0; l < LL; ++l) {
        P[l] = -(eb[(size_t)l * NNPX] + P[l] * rinv);
        mx = fmaxf(mx, P[l]);
    }
    float ssum = 0.f;
    for (int l = 0; l < LL; ++l) { P[l] = __builtin_amdgcn_exp2f((P[l] - mx) * LOG2E); ssum += P[l]; }
    float rs = __builtin_amdgcn_rcpf(ssum);
    for (int l = 0; l < LL; ++l) P[l] *= rs;

    if (LAST) {
        float* ob = Out + (size_t)b * LL * NNPX + n;
        for (int l = 0; l < LL; ++l) ob[(size_t)l * NNPX] = P[l];
    } else {
        __hip_bfloat16* mq = MQ + (size_t)b * LCH * NNPX + n;
        for (int k = 0; k < LL; ++k) {
            float a = 0.f;
            for (int l = 0; l < LL; ++l) a += muS[k * LL + l] * P[l];
            mq[(size_t)k * NNPX] = __float2bfloat16(a);
        }
        // channels 21..31 keep their k_prep values (1.0, zeros)
    }
}

extern "C" void kernel_launch(void* const* d_in, const int* in_sizes, int n_in,
                              void* d_out, int out_size, void* d_ws, size_t ws_size,
                              hipStream_t stream) {
    const float* E0   = (const float*)d_in[0];
    const float* Refs = (const float*)d_in[1];
    const float* Mu   = (const float*)d_in[2];
    float* out = (float*)d_out;

    char* w = (char*)d_ws;
    size_t off = 0;
    auto alloc = [&](size_t bytes) {
        void* p = w + off;
        off += (bytes + 255) & ~(size_t)255;
        return p;
    };
    float4* FN = (float4*)alloc((size_t)BB * NNPX * sizeof(float4));
    float4* FS = (float4*)alloc((size_t)BB * NNPX * sizeof(float4));
    __hip_bfloat16* MQbf = (__hip_bfloat16*)alloc((size_t)BB * LCH * NNPX * sizeof(__hip_bfloat16));

    // m-split S whose partial buffer fits in remaining ws (cap 8)
    size_t per = (size_t)BB * LLP * NNPX * sizeof(float);
    size_t avail = ws_size > off ? ws_size - off : 0;
    int Smax = (int)(avail / (per + 256));
    static const int divs[] = {8, 6, 4, 3, 2, 1};
    int S = 1;
    for (int i = 0; i < 6; ++i) if (divs[i] <= Smax) { S = divs[i]; break; }
    float* Ppart = (float*)alloc((size_t)S * per);

    k_prep<<<BB * NNPX / 256, 256, 0, stream>>>(E0, Refs, Mu, FN, FS, MQbf);
    for (int it = 0; it < NITERS; ++it) {
        k_accum<<<dim3(288, S), 256, 0, stream>>>(FS, FN, (const unsigned short*)MQbf, Ppart, S);
        if (it == NITERS - 1)
            k_softmax<true><<<BB * NNPX / 256, 256, 0, stream>>>(E0, Ppart, Mu, MQbf, out, S);
        else
            k_softmax<false><<<BB * NNPX / 256, 256, 0, stream>>>(E0, Ppart, Mu, MQbf, out, S);
    }
}